// Round 4
// baseline (1055.040 us; speedup 1.0000x reference)
//
#include <hip/hip_runtime.h>
#include <math.h>

#define BB 8
#define TT 2048
#define FF 67
#define DD 64
#define BT (BB * TT)
#define JITTER 1e-6f

// ---- bf16 helpers (manual RNE pack, shift/and unpack) -----------------------
__device__ __forceinline__ unsigned int f2bf(float f) {
  unsigned int u = __float_as_uint(f);
  return (u + 0x7fffu + ((u >> 16) & 1u)) >> 16;
}
__device__ __forceinline__ float bf_lo(unsigned int u) {
  return __uint_as_float(u << 16);
}
__device__ __forceinline__ float bf_hi(unsigned int u) {
  return __uint_as_float(u & 0xffff0000u);
}

// ---------------- kernel A: pack z->bf16 + per-row stats ---------------------
// 8 lanes per row, each packs 8 d's into one uint4 (bf16x8).
__global__ __launch_bounds__(256) void pack_stats_kernel(
    const float* __restrict__ in, float* __restrict__ out_mean,
    float* __restrict__ c, float* __restrict__ noise,
    uint4* __restrict__ zp4) {
  int g = blockIdx.x * 256 + threadIdx.x;   // 0 .. BT*8-1
  int row = g >> 3, dc = g & 7;
  const float* p = in + (size_t)row * FF + 1 + dc * 8;
  float sq = 0.f;
  unsigned int w[4];
#pragma unroll
  for (int k = 0; k < 4; ++k) {
    float a = p[2 * k] * 0.125f;
    float b2 = p[2 * k + 1] * 0.125f;
    sq += a * a + b2 * b2;
    w[k] = f2bf(a) | (f2bf(b2) << 16);
  }
  uint4 pk;
  pk.x = w[0]; pk.y = w[1]; pk.z = w[2]; pk.w = w[3];
  zp4[(size_t)row * 8 + dc] = pk;
  sq += __shfl_xor(sq, 1);
  sq += __shfl_xor(sq, 2);
  sq += __shfl_xor(sq, 4);
  if (dc == 0) {
    const float* r = in + (size_t)row * FF;
    out_mean[row] = r[0];
    float v = r[1 + DD];
    float x = r[1 + DD + 1];
    float sp = fmaxf(x, 0.f) + log1pf(__expf(-fabsf(x)));
    c[row] = v * __expf(-0.5f * sq);
    noise[row] = sp;
  }
}

// ---------------- fallback per-row stats (small ws) --------------------------
__global__ __launch_bounds__(256) void row_stats_kernel(
    const float* __restrict__ in, float* __restrict__ out_mean,
    float* __restrict__ c, float* __restrict__ noise) {
  int idx = blockIdx.x * 256 + threadIdx.x;
  if (idx >= BT) return;
  const float* row = in + (size_t)idx * FF;
  out_mean[idx] = row[0];
  float sq = 0.f;
#pragma unroll
  for (int d = 0; d < DD; ++d) {
    float z = row[1 + d] * 0.125f;
    sq = fmaf(z, z, sq);
  }
  float v = row[1 + DD];
  float x = row[1 + DD + 1];
  float sp = fmaxf(x, 0.f) + log1pf(__expf(-fabsf(x)));
  c[idx] = v * __expf(-0.5f * sq);
  noise[idx] = sp;
}

// one bf16x8 word-dot step: acc[a][q] += dot over the 2 bf16 in word WX
#define DOT_WORD(WX)                                                    \
  {                                                                     \
    float fa0[8], fa1[8], fb0[4], fb1[4];                               \
    _Pragma("unroll") for (int a = 0; a < 8; ++a) {                     \
      fa0[a] = bf_lo(ai[a].WX);                                         \
      fa1[a] = bf_hi(ai[a].WX);                                         \
    }                                                                   \
    _Pragma("unroll") for (int q = 0; q < 4; ++q) {                     \
      fb0[q] = bf_lo(bj[q].WX);                                         \
      fb1[q] = bf_hi(bj[q].WX);                                         \
    }                                                                   \
    _Pragma("unroll") for (int a = 0; a < 8; ++a)                       \
        _Pragma("unroll") for (int q = 0; q < 4; ++q) acc[a][q] =       \
        fmaf(fa0[a], fb0[q], fmaf(fa1[a], fb1[q], acc[a][q]));          \
  }

// ---------------- kernel B: triangular 128x128 tiles, strip-pipelined --------
// LDS: bf16 z panels, 2 x 16KB. One barrier total; two 128x64 j-strips whose
// stores drain under the next strip's FMA (no barriers after stage).
template <bool PACKED>
__global__ __launch_bounds__(256, 3) void cov_kernel(
    const float* __restrict__ in, const uint4* __restrict__ zp4,
    const float* __restrict__ c, const float* __restrict__ noise,
    float* __restrict__ out_f, float* __restrict__ out_y) {
  __shared__ uint4 lds[2048];   // zi: [0..1023], zj: [1024..2047]  (32 KB)

  // tiles 0..119 strict lower (heavy) first, 120..135 diagonal (light) last
  int k = blockIdx.x;
  int ti, tj;
  if (k < 120) {
    ti = (int)((1.0f + sqrtf(1.0f + 8.0f * (float)k)) * 0.5f);
    while (ti * (ti - 1) / 2 > k) --ti;
    while ((ti + 1) * ti / 2 <= k) ++ti;
    tj = k - ti * (ti - 1) / 2;
  } else {
    ti = tj = k - 120;
  }
  const int b = blockIdx.y;
  const int gi0 = ti * 128, gj0 = tj * 128;
  const int t = threadIdx.x;
  const bool diag = (ti == tj);

  // ---- stage both 128x64 bf16 panels (chunk-XOR swizzle (row>>3)&7) ----
  if (PACKED) {
    const uint4* si = zp4 + (size_t)(b * TT + gi0) * 8;
    const uint4* sj = zp4 + (size_t)(b * TT + gj0) * 8;
#pragma unroll
    for (int kk = 0; kk < 4; ++kk) {
      int idx = kk * 256 + t;
      int row = idx >> 3, ch = idx & 7;
      int sw = (row >> 3) & 7;
      lds[row * 8 + (ch ^ sw)] = si[idx];
      lds[1024 + row * 8 + (ch ^ sw)] = sj[idx];
    }
  } else {
#pragma unroll
    for (int kk = 0; kk < 4; ++kk) {
      int idx = kk * 256 + t;
      int row = idx >> 3, ch = idx & 7;
      int sw = (row >> 3) & 7;
      const float* pi = in + (size_t)(b * TT + gi0 + row) * FF + 1 + ch * 8;
      const float* pj = in + (size_t)(b * TT + gj0 + row) * FF + 1 + ch * 8;
      unsigned int wi[4], wj[4];
#pragma unroll
      for (int e = 0; e < 4; ++e) {
        wi[e] = f2bf(pi[2 * e] * 0.125f) | (f2bf(pi[2 * e + 1] * 0.125f) << 16);
        wj[e] = f2bf(pj[2 * e] * 0.125f) | (f2bf(pj[2 * e + 1] * 0.125f) << 16);
      }
      uint4 ui, uj;
      ui.x = wi[0]; ui.y = wi[1]; ui.z = wi[2]; ui.w = wi[3];
      uj.x = wj[0]; uj.y = wj[1]; uj.z = wj[2]; uj.w = wj[3];
      lds[row * 8 + (ch ^ sw)] = ui;
      lds[1024 + row * 8 + (ch ^ sw)] = uj;
    }
  }
  __syncthreads();   // the ONLY barrier

  const int tx = t & 15, ty = t >> 4;
  const int i0 = ty * 8;
  const int swi = ty & 7;
  const int swj = (tx >> 1) & 7;

  const size_t TTT = (size_t)TT * TT;
  const size_t obase = (size_t)b * TTT;
  const float* cb = c + b * TT;

  float ci[8];
#pragma unroll
  for (int a = 0; a < 8; ++a) ci[a] = cb[gi0 + i0 + a];

#pragma unroll
  for (int s = 0; s < 2; ++s) {
    const int jbase = s * 64 + tx * 4;   // col within tile
    float acc[8][4] = {};

#pragma unroll
    for (int dc = 0; dc < 8; ++dc) {
      uint4 ai[8], bj[4];
#pragma unroll
      for (int a = 0; a < 8; ++a) ai[a] = lds[(i0 + a) * 8 + (dc ^ swi)];
#pragma unroll
      for (int q = 0; q < 4; ++q)
        bj[q] = lds[1024 + (jbase + q) * 8 + (dc ^ swj)];
      DOT_WORD(x)
      DOT_WORD(y)
      DOT_WORD(z)
      DOT_WORD(w)
    }

    // epilogue: f = exp(acc)*ci*cj (reuse acc), then direct + mirror stores
    float cj[4];
#pragma unroll
    for (int q = 0; q < 4; ++q) cj[q] = cb[gj0 + jbase + q];
#pragma unroll
    for (int a = 0; a < 8; ++a)
#pragma unroll
      for (int q = 0; q < 4; ++q)
        acc[a][q] = __expf(acc[a][q]) * ci[a] * cj[q];

#pragma unroll
    for (int a = 0; a < 8; ++a) {
      int gi = gi0 + i0 + a;
      float fv[4], yv[4];
#pragma unroll
      for (int q = 0; q < 4; ++q) {
        float ff = acc[a][q];
        float yy = ff;
        if (diag && (i0 + a == jbase + q)) {
          ff += JITTER;
          yy = ff + noise[b * TT + gi];
        }
        fv[q] = ff;
        yv[q] = yy;
      }
      size_t off = obase + (size_t)gi * TT + gj0 + jbase;
      *reinterpret_cast<float4*>(out_f + off) =
          make_float4(fv[0], fv[1], fv[2], fv[3]);
      *reinterpret_cast<float4*>(out_y + off) =
          make_float4(yv[0], yv[1], yv[2], yv[3]);
    }

    if (!diag) {
#pragma unroll
      for (int q = 0; q < 4; ++q) {
        size_t off = obase + (size_t)(gj0 + jbase + q) * TT + gi0 + i0;
        float4 lo = make_float4(acc[0][q], acc[1][q], acc[2][q], acc[3][q]);
        float4 hi = make_float4(acc[4][q], acc[5][q], acc[6][q], acc[7][q]);
        *reinterpret_cast<float4*>(out_f + off) = lo;
        *reinterpret_cast<float4*>(out_f + off + 4) = hi;
        *reinterpret_cast<float4*>(out_y + off) = lo;
        *reinterpret_cast<float4*>(out_y + off + 4) = hi;
      }
    }
  }
}

extern "C" void kernel_launch(void* const* d_in, const int* in_sizes, int n_in,
                              void* d_out, int out_size, void* d_ws,
                              size_t ws_size, hipStream_t stream) {
  const float* in = (const float*)d_in[0];
  float* out = (float*)d_out;
  float* c = (float*)d_ws;                           // BT floats
  float* noise = c + BT;                             // BT floats
  uint4* zp4 = (uint4*)((char*)d_ws + (size_t)2 * BT * 4);  // BT*64 bf16 = 2MB
  float* out_mean = out;                             // BT
  float* out_f = out + BT;                           // BB*TT*TT
  float* out_y = out_f + (size_t)BB * TT * TT;

  const size_t need = (size_t)2 * BT * 4 + (size_t)BT * DD * 2;
  if (ws_size >= need) {
    pack_stats_kernel<<<(BT * 8) / 256, 256, 0, stream>>>(in, out_mean, c,
                                                          noise, zp4);
    cov_kernel<true><<<dim3(136, BB), 256, 0, stream>>>(in, zp4, c, noise,
                                                        out_f, out_y);
  } else {
    row_stats_kernel<<<BT / 256, 256, 0, stream>>>(in, out_mean, c, noise);
    cov_kernel<false><<<dim3(136, BB), 256, 0, stream>>>(in, zp4, c, noise,
                                                         out_f, out_y);
  }
}

// Round 5
// 286.835 us; speedup vs baseline: 3.6782x; 3.6782x over previous
//
#include <hip/hip_runtime.h>
#include <math.h>

#define BB 8
#define TT 2048
#define FF 67
#define DD 64
#define BT (BB * TT)
#define JITTER 1e-6f

#define NT 32                 // 64-wide tiles per dim
#define NOFF 496              // strict-lower tiles (32*31/2)
#define NTILE 528             // per-batch tiles (NOFF + 32 diag)
#define NITEM (BB * NTILE)    // 4224 work items
#define GRID 512              // persistent blocks (2 per CU)

// ---------------- kernel A: pack scaled z (f32) + per-row stats --------------
__global__ __launch_bounds__(256) void pack_stats_kernel(
    const float* __restrict__ in, float* __restrict__ out_mean,
    float* __restrict__ c, float* __restrict__ noise,
    float4* __restrict__ zp4) {
  int g = blockIdx.x * 256 + threadIdx.x;   // 0 .. BT*16-1
  int row = g >> 4, dc = g & 15;
  const float* p = in + (size_t)row * FF + 1 + dc * 4;
  float z0 = p[0] * 0.125f, z1 = p[1] * 0.125f;
  float z2 = p[2] * 0.125f, z3 = p[3] * 0.125f;
  zp4[(size_t)row * 16 + dc] = make_float4(z0, z1, z2, z3);
  float sq = z0 * z0 + z1 * z1 + z2 * z2 + z3 * z3;
  sq += __shfl_xor(sq, 1);
  sq += __shfl_xor(sq, 2);
  sq += __shfl_xor(sq, 4);
  sq += __shfl_xor(sq, 8);
  if (dc == 0) {
    const float* r = in + (size_t)row * FF;
    out_mean[row] = r[0];
    float v = r[1 + DD];
    float x = r[1 + DD + 1];
    float sp = fmaxf(x, 0.f) + log1pf(__expf(-fabsf(x)));
    c[row] = v * __expf(-0.5f * sq);
    noise[row] = sp;
  }
}

// ---------------- fallback per-row stats (small ws) --------------------------
__global__ __launch_bounds__(256) void row_stats_kernel(
    const float* __restrict__ in, float* __restrict__ out_mean,
    float* __restrict__ c, float* __restrict__ noise) {
  int idx = blockIdx.x * 256 + threadIdx.x;
  if (idx >= BT) return;
  const float* row = in + (size_t)idx * FF;
  out_mean[idx] = row[0];
  float sq = 0.f;
#pragma unroll
  for (int d = 0; d < DD; ++d) {
    float z = row[1 + d] * 0.125f;
    sq = fmaf(z, z, sq);
  }
  float v = row[1 + DD];
  float x = row[1 + DD + 1];
  float sp = fmaxf(x, 0.f) + log1pf(__expf(-fabsf(x)));
  c[idx] = v * __expf(-0.5f * sq);
  noise[idx] = sp;
}

// item wid -> (batch, ti, tj); off-diag items [0, 8*NOFF), diag last (tail)
__device__ __forceinline__ void decode_item(int wid, int& b, int& ti,
                                            int& tj) {
  if (wid < BB * NOFF) {
    b = wid & 7;
    int k = wid >> 3;   // strict lower: k = ti*(ti-1)/2 + tj, tj < ti
    int x = (int)((1.0f + sqrtf(1.0f + 8.0f * (float)k)) * 0.5f);
    while (x * (x - 1) / 2 > k) --x;
    while ((x + 1) * x / 2 <= k) ++x;
    ti = x;
    tj = k - x * (x - 1) / 2;
  } else {
    int r = wid - BB * NOFF;
    b = r & 7;
    ti = tj = r >> 3;
  }
}

// ---------------- kernel B: persistent-block 64x64 triangular tiles ----------
// 2 blocks/CU; per item: ds_write staged regs -> barrier -> prefetch next item
// to regs (T14) -> FMA+epilogue+fire-and-forget stores -> barrier. Stores of
// item t drain under compute of item t+1.
template <bool PACKED>
__global__ __launch_bounds__(256) void cov_kernel(
    const float* __restrict__ in, const float4* __restrict__ zp4,
    const float* __restrict__ c, const float* __restrict__ noise,
    float* __restrict__ out_f, float* __restrict__ out_y) {
  __shared__ float4 lds[2048];   // zi [0..1023], zj [1024..2047]  (32 KB)

  const int t = threadIdx.x;
  const int bid = blockIdx.x;
  const int tx = t & 15, ty = t >> 4;
  const int i0 = ty * 4, j0 = tx * 4;
  const int swi = ty >> 1, swj = tx >> 1;
  const size_t TTT = (size_t)TT * TT;

  const int nit = (NITEM - bid + GRID - 1) / GRID;
  if (nit <= 0) return;

  float4 pf[8];
  int cb, cti, ctj;

  // prefetch item 0
  {
    decode_item(bid, cb, cti, ctj);
#pragma unroll
    for (int kk = 0; kk < 4; ++kk) {
      int idx = kk * 256 + t;
      int row = idx >> 4, ch = idx & 15;
      if (PACKED) {
        pf[kk] = zp4[(size_t)(cb * TT + cti * 64 + row) * 16 + ch];
        pf[4 + kk] = zp4[(size_t)(cb * TT + ctj * 64 + row) * 16 + ch];
      } else {
        const float* pi = in + (size_t)(cb * TT + cti * 64 + row) * FF + 1 + ch * 4;
        const float* pj = in + (size_t)(cb * TT + ctj * 64 + row) * FF + 1 + ch * 4;
        pf[kk] = make_float4(pi[0] * 0.125f, pi[1] * 0.125f, pi[2] * 0.125f,
                             pi[3] * 0.125f);
        pf[4 + kk] = make_float4(pj[0] * 0.125f, pj[1] * 0.125f, pj[2] * 0.125f,
                                 pj[3] * 0.125f);
      }
    }
  }

  int wid = bid;
  for (int it = 0; it < nit; ++it) {
    // ---- stage current item's panels (chunk-XOR swizzle) ----
#pragma unroll
    for (int kk = 0; kk < 4; ++kk) {
      int idx = kk * 256 + t;
      int row = idx >> 4, ch = idx & 15;
      int sw = (row >> 3) & 7;
      lds[row * 16 + (ch ^ sw)] = pf[kk];
      lds[1024 + row * 16 + (ch ^ sw)] = pf[4 + kk];
    }
    __syncthreads();

    const int b = cb, ti = cti, tj = ctj;
    const bool diag = (ti == tj);
    const int gi0 = ti * 64, gj0 = tj * 64;

    // ---- prefetch next item into regs (drains under this item's compute) ----
    wid += GRID;
    if (it + 1 < nit) {
      decode_item(wid, cb, cti, ctj);
#pragma unroll
      for (int kk = 0; kk < 4; ++kk) {
        int idx = kk * 256 + t;
        int row = idx >> 4, ch = idx & 15;
        if (PACKED) {
          pf[kk] = zp4[(size_t)(cb * TT + cti * 64 + row) * 16 + ch];
          pf[4 + kk] = zp4[(size_t)(cb * TT + ctj * 64 + row) * 16 + ch];
        } else {
          const float* pi =
              in + (size_t)(cb * TT + cti * 64 + row) * FF + 1 + ch * 4;
          const float* pj =
              in + (size_t)(cb * TT + ctj * 64 + row) * FF + 1 + ch * 4;
          pf[kk] = make_float4(pi[0] * 0.125f, pi[1] * 0.125f, pi[2] * 0.125f,
                               pi[3] * 0.125f);
          pf[4 + kk] = make_float4(pj[0] * 0.125f, pj[1] * 0.125f,
                                   pj[2] * 0.125f, pj[3] * 0.125f);
        }
      }
    }

    // ---- compute 4x4 micro-tile over 16 float4 d-chunks ----
    float acc[4][4] = {};
#pragma unroll
    for (int dc = 0; dc < 16; ++dc) {
      float4 af[4], bf[4];
#pragma unroll
      for (int a = 0; a < 4; ++a) af[a] = lds[(i0 + a) * 16 + (dc ^ swi)];
#pragma unroll
      for (int q = 0; q < 4; ++q)
        bf[q] = lds[1024 + (j0 + q) * 16 + (dc ^ swj)];
#pragma unroll
      for (int a = 0; a < 4; ++a)
#pragma unroll
        for (int q = 0; q < 4; ++q) {
          acc[a][q] = fmaf(af[a].x, bf[q].x, acc[a][q]);
          acc[a][q] = fmaf(af[a].y, bf[q].y, acc[a][q]);
          acc[a][q] = fmaf(af[a].z, bf[q].z, acc[a][q]);
          acc[a][q] = fmaf(af[a].w, bf[q].w, acc[a][q]);
        }
    }

    // ---- epilogue: f = exp(acc)*ci*cj ----
    const float* cbp = c + b * TT;
    float ci[4], cj[4];
#pragma unroll
    for (int a = 0; a < 4; ++a) ci[a] = cbp[gi0 + i0 + a];
#pragma unroll
    for (int q = 0; q < 4; ++q) cj[q] = cbp[gj0 + j0 + q];
#pragma unroll
    for (int a = 0; a < 4; ++a)
#pragma unroll
      for (int q = 0; q < 4; ++q)
        acc[a][q] = __expf(acc[a][q]) * ci[a] * cj[q];

    const size_t obase = (size_t)b * TTT;

    // ---- direct tile stores (fully coalesced float4 rows) ----
#pragma unroll
    for (int a = 0; a < 4; ++a) {
      int gi = gi0 + i0 + a;
      float fv[4], yv[4];
#pragma unroll
      for (int q = 0; q < 4; ++q) {
        float ff = acc[a][q];
        float yy = ff;
        if (diag && (i0 + a == j0 + q)) {
          ff += JITTER;
          yy = ff + noise[b * TT + gi];
        }
        fv[q] = ff;
        yv[q] = yy;
      }
      size_t off = obase + (size_t)gi * TT + gj0 + j0;
      *reinterpret_cast<float4*>(out_f + off) =
          make_float4(fv[0], fv[1], fv[2], fv[3]);
      *reinterpret_cast<float4*>(out_y + off) =
          make_float4(yv[0], yv[1], yv[2], yv[3]);
    }

    // ---- mirror tile stores (off-diag only; y == f exactly) ----
    if (!diag) {
#pragma unroll
      for (int q = 0; q < 4; ++q) {
        size_t off = obase + (size_t)(gj0 + j0 + q) * TT + gi0 + i0;
        float4 v = make_float4(acc[0][q], acc[1][q], acc[2][q], acc[3][q]);
        *reinterpret_cast<float4*>(out_f + off) = v;
        *reinterpret_cast<float4*>(out_y + off) = v;
      }
    }
    __syncthreads();   // LDS reads done before next item's stage
  }
}

extern "C" void kernel_launch(void* const* d_in, const int* in_sizes, int n_in,
                              void* d_out, int out_size, void* d_ws,
                              size_t ws_size, hipStream_t stream) {
  const float* in = (const float*)d_in[0];
  float* out = (float*)d_out;
  float* c = (float*)d_ws;                              // BT floats
  float* noise = c + BT;                                // BT floats
  float4* zp4 = (float4*)((char*)d_ws + (size_t)2 * BT * 4);  // BT*DD f32 (4MB)
  float* out_mean = out;                                // BT
  float* out_f = out + BT;                              // BB*TT*TT
  float* out_y = out_f + (size_t)BB * TT * TT;

  const size_t need = (size_t)2 * BT * 4 + (size_t)BT * DD * 4;
  if (ws_size >= need) {
    pack_stats_kernel<<<(BT * 16) / 256, 256, 0, stream>>>(in, out_mean, c,
                                                           noise, zp4);
    cov_kernel<true><<<GRID, 256, 0, stream>>>(in, zp4, c, noise, out_f,
                                               out_y);
  } else {
    row_stats_kernel<<<BT / 256, 256, 0, stream>>>(in, out_mean, c, noise);
    cov_kernel<false><<<GRID, 256, 0, stream>>>(in, zp4, c, noise, out_f,
                                                out_y);
  }
}

// Round 6
// 128.071 us; speedup vs baseline: 8.2380x; 2.2397x over previous
//
#include <hip/hip_runtime.h>
#include <math.h>

#define BB 8
#define TT 2048
#define FF 67
#define DD 64
#define BT (BB * TT)
#define JITTER 1e-6f

#define NT 32                  // 64-wide tiles per dim
#define NOFF 496               // strict-lower tiles per batch
#define NOFFB (BB * NOFF)      // 3968 off-diag blocks (first)
#define NBLK (NOFFB + BB * NT) // + 256 diag blocks (tail) = 4224

typedef float f4v __attribute__((ext_vector_type(4)));
__device__ __forceinline__ void nt_store4(float* p, float a, float b, float c,
                                          float d) {
  f4v w = {a, b, c, d};
  __builtin_nontemporal_store(w, (f4v*)p);
}

// ---------------- kernel A: pack scaled z (f32) + per-row stats --------------
__global__ __launch_bounds__(256) void pack_stats_kernel(
    const float* __restrict__ in, float* __restrict__ out_mean,
    float* __restrict__ c, float* __restrict__ noise,
    float4* __restrict__ zp4) {
  int g = blockIdx.x * 256 + threadIdx.x;   // 0 .. BT*16-1
  int row = g >> 4, dc = g & 15;
  const float* p = in + (size_t)row * FF + 1 + dc * 4;
  float z0 = p[0] * 0.125f, z1 = p[1] * 0.125f;
  float z2 = p[2] * 0.125f, z3 = p[3] * 0.125f;
  zp4[(size_t)row * 16 + dc] = make_float4(z0, z1, z2, z3);
  float sq = z0 * z0 + z1 * z1 + z2 * z2 + z3 * z3;
  sq += __shfl_xor(sq, 1);
  sq += __shfl_xor(sq, 2);
  sq += __shfl_xor(sq, 4);
  sq += __shfl_xor(sq, 8);
  if (dc == 0) {
    const float* r = in + (size_t)row * FF;
    out_mean[row] = r[0];
    float v = r[1 + DD];
    float x = r[1 + DD + 1];
    float sp = fmaxf(x, 0.f) + log1pf(__expf(-fabsf(x)));
    c[row] = v * __expf(-0.5f * sq);
    noise[row] = sp;
  }
}

// ---------------- fallback per-row stats (small ws) --------------------------
__global__ __launch_bounds__(256) void row_stats_kernel(
    const float* __restrict__ in, float* __restrict__ out_mean,
    float* __restrict__ c, float* __restrict__ noise) {
  int idx = blockIdx.x * 256 + threadIdx.x;
  if (idx >= BT) return;
  const float* row = in + (size_t)idx * FF;
  out_mean[idx] = row[0];
  float sq = 0.f;
#pragma unroll
  for (int d = 0; d < DD; ++d) {
    float z = row[1 + d] * 0.125f;
    sq = fmaf(z, z, sq);
  }
  float v = row[1 + DD];
  float x = row[1 + DD + 1];
  float sp = fmaxf(x, 0.f) + log1pf(__expf(-fabsf(x)));
  c[idx] = v * __expf(-0.5f * sq);
  noise[idx] = sp;
}

// ---------------- kernel B: one-shot 64x64 triangular tiles ------------------
// 32 KB LDS (two 64x64 f32 panels, sw=(row>>2)&7 XOR swizzle) -> 5 blocks/CU.
// Mirror tile staged via LDS transpose (aliases dead A panel) so ALL output
// stores are 256B-contiguous full-line nontemporal float4.
template <bool PACKED>
__global__ __launch_bounds__(256) void cov_kernel(
    const float* __restrict__ in, const float4* __restrict__ zp4,
    const float* __restrict__ c, const float* __restrict__ noise,
    float* __restrict__ out_f, float* __restrict__ out_y) {
  __shared__ float4 lds[2048];   // A: [0..1023], B: [1024..2047]; ft aliases A

  // decode block -> (b, ti, tj); batch-major so neighbors share the i-panel
  int wid = blockIdx.x;
  int b, ti, tj;
  if (wid < NOFFB) {
    b = wid / NOFF;
    int k = wid - b * NOFF;          // k = ti*(ti-1)/2 + tj, tj < ti
    int x = (int)((1.0f + sqrtf(1.0f + 8.0f * (float)k)) * 0.5f);
    while (x * (x - 1) / 2 > k) --x;
    while ((x + 1) * x / 2 <= k) ++x;
    ti = x;
    tj = k - x * (x - 1) / 2;
  } else {
    int r = wid - NOFFB;
    b = r >> 5;
    ti = tj = r & 31;
  }
  const bool diag = (ti == tj);
  const int gi0 = ti * 64, gj0 = tj * 64;
  const int t = threadIdx.x;

  // ---- stage panels (sw=(row>>2)&7) ----
#pragma unroll
  for (int kk = 0; kk < 4; ++kk) {
    int idx = kk * 256 + t;
    int row = idx >> 4, ch = idx & 15;
    int sw = (row >> 2) & 7;
    float4 av, bv;
    if (PACKED) {
      av = zp4[(size_t)(b * TT + gi0 + row) * 16 + ch];
      bv = zp4[(size_t)(b * TT + gj0 + row) * 16 + ch];
    } else {
      const float* pi = in + (size_t)(b * TT + gi0 + row) * FF + 1 + ch * 4;
      const float* pj = in + (size_t)(b * TT + gj0 + row) * FF + 1 + ch * 4;
      av = make_float4(pi[0] * 0.125f, pi[1] * 0.125f, pi[2] * 0.125f,
                       pi[3] * 0.125f);
      bv = make_float4(pj[0] * 0.125f, pj[1] * 0.125f, pj[2] * 0.125f,
                       pj[3] * 0.125f);
    }
    lds[row * 16 + (ch ^ sw)] = av;
    lds[1024 + row * 16 + (ch ^ sw)] = bv;
  }
  __syncthreads();

  const int tx = t & 15, ty = t >> 4;
  const int i0 = ty * 4, j0 = tx * 4;
  const int swi = ty & 7, swj = tx & 7;

  // ---- 4x4 micro-tile over 16 float4 d-chunks ----
  float acc[4][4] = {};
#pragma unroll
  for (int dc = 0; dc < 16; ++dc) {
    float4 af[4], bf[4];
#pragma unroll
    for (int a = 0; a < 4; ++a) af[a] = lds[(i0 + a) * 16 + (dc ^ swi)];
#pragma unroll
    for (int q = 0; q < 4; ++q)
      bf[q] = lds[1024 + (j0 + q) * 16 + (dc ^ swj)];
#pragma unroll
    for (int a = 0; a < 4; ++a)
#pragma unroll
      for (int q = 0; q < 4; ++q) {
        acc[a][q] = fmaf(af[a].x, bf[q].x, acc[a][q]);
        acc[a][q] = fmaf(af[a].y, bf[q].y, acc[a][q]);
        acc[a][q] = fmaf(af[a].z, bf[q].z, acc[a][q]);
        acc[a][q] = fmaf(af[a].w, bf[q].w, acc[a][q]);
      }
  }

  // ---- f = exp(acc)*ci*cj ----
  const float* cbp = c + b * TT;
  float ci[4], cj[4];
#pragma unroll
  for (int a = 0; a < 4; ++a) ci[a] = cbp[gi0 + i0 + a];
#pragma unroll
  for (int q = 0; q < 4; ++q) cj[q] = cbp[gj0 + j0 + q];
#pragma unroll
  for (int a = 0; a < 4; ++a)
#pragma unroll
    for (int q = 0; q < 4; ++q)
      acc[a][q] = __expf(acc[a][q]) * ci[a] * cj[q];

  const size_t TTT = (size_t)TT * TT;
  const size_t obase = (size_t)b * TTT;

  // ---- direct tile: full-line nontemporal stores ----
#pragma unroll
  for (int a = 0; a < 4; ++a) {
    int gi = gi0 + i0 + a;
    float fv[4], yv[4];
#pragma unroll
    for (int q = 0; q < 4; ++q) {
      float ff = acc[a][q];
      float yy = ff;
      if (diag && (i0 + a == j0 + q)) {
        ff += JITTER;
        yy = ff + noise[b * TT + gi];
      }
      fv[q] = ff;
      yv[q] = yy;
    }
    size_t off = obase + (size_t)gi * TT + gj0 + j0;
    nt_store4(out_f + off, fv[0], fv[1], fv[2], fv[3]);
    nt_store4(out_y + off, yv[0], yv[1], yv[2], yv[3]);
  }

  // ---- mirror tile (off-diag): LDS transpose -> full-line stores ----
  if (!diag) {
    __syncthreads();   // panel A reads done everywhere
    // ft[j][i] as [64 rows][16 f4], sw=(row>>2)&7; thread writes float4 over a
#pragma unroll
    for (int q = 0; q < 4; ++q) {
      int jr = j0 + q;                       // row of ft = column of tile
      int sw = tx & 7;                       // (jr>>2)&7 == tx&7
      lds[jr * 16 + ((ty) ^ sw)] =           // chunk index over i = ty
          make_float4(acc[0][q], acc[1][q], acc[2][q], acc[3][q]);
    }
    __syncthreads();
#pragma unroll
    for (int kk = 0; kk < 4; ++kk) {
      int idx = kk * 256 + t;
      int jr = idx >> 4, kc = idx & 15;
      int sw = (jr >> 2) & 7;
      float4 v = lds[jr * 16 + (kc ^ sw)];
      size_t off = obase + (size_t)(gj0 + jr) * TT + gi0 + kc * 4;
      nt_store4(out_f + off, v.x, v.y, v.z, v.w);
      nt_store4(out_y + off, v.x, v.y, v.z, v.w);
    }
  }
}

extern "C" void kernel_launch(void* const* d_in, const int* in_sizes, int n_in,
                              void* d_out, int out_size, void* d_ws,
                              size_t ws_size, hipStream_t stream) {
  const float* in = (const float*)d_in[0];
  float* out = (float*)d_out;
  float* c = (float*)d_ws;                              // BT floats
  float* noise = c + BT;                                // BT floats
  float4* zp4 = (float4*)((char*)d_ws + (size_t)2 * BT * 4);  // BT*DD f32
  float* out_mean = out;                                // BT
  float* out_f = out + BT;                              // BB*TT*TT
  float* out_y = out_f + (size_t)BB * TT * TT;

  const size_t need = (size_t)2 * BT * 4 + (size_t)BT * DD * 4;
  if (ws_size >= need) {
    pack_stats_kernel<<<(BT * 16) / 256, 256, 0, stream>>>(in, out_mean, c,
                                                           noise, zp4);
    cov_kernel<true><<<NBLK, 256, 0, stream>>>(in, zp4, c, noise, out_f,
                                               out_y);
  } else {
    row_stats_kernel<<<BT / 256, 256, 0, stream>>>(in, out_mean, c, noise);
    cov_kernel<false><<<NBLK, 256, 0, stream>>>(in, zp4, c, noise, out_f,
                                                out_y);
  }
}